// Round 1
// baseline (1389.510 us; speedup 1.0000x reference)
//
#include <hip/hip_runtime.h>
#include <hip/hip_bf16.h>
#include <math.h>

#define NNODES 20000
#define NEDGES 400000
#define NREL 8

// ---------------------------------------------------------------------------
// Edge preprocessing: degree histogram + per-(node,rel) counts
// ---------------------------------------------------------------------------
__global__ void count_edges(const int* __restrict__ ei, const int* __restrict__ et,
                            int* __restrict__ deg, int* __restrict__ rel_cnt, int E) {
    int e = blockIdx.x * blockDim.x + threadIdx.x;
    if (e >= E) return;
    int d = ei[E + e];            // dst row of edge_index
    atomicAdd(&deg[d], 1);
    atomicAdd(&rel_cnt[d * NREL + et[e]], 1);
}

// Single-block exclusive scan over deg[0..n-1] -> off[0..n], cursor copy.
__global__ void scan_kernel(const int* __restrict__ deg, int* __restrict__ off,
                            int* __restrict__ cursor, int n) {
    __shared__ int buf[1024];
    __shared__ int carry;
    if (threadIdx.x == 0) carry = 0;
    __syncthreads();
    for (int base = 0; base < n; base += 1024) {
        int i = base + (int)threadIdx.x;
        int v = (i < n) ? deg[i] : 0;
        buf[threadIdx.x] = v;
        __syncthreads();
        // Hillis-Steele inclusive scan
        for (int ofs = 1; ofs < 1024; ofs <<= 1) {
            int t = (threadIdx.x >= (unsigned)ofs) ? buf[threadIdx.x - ofs] : 0;
            __syncthreads();
            buf[threadIdx.x] += t;
            __syncthreads();
        }
        int incl = buf[threadIdx.x];
        int excl = incl - v;
        if (i < n) { off[i] = carry + excl; cursor[i] = carry + excl; }
        __syncthreads();
        if (threadIdx.x == 1023) carry += incl;
        __syncthreads();
    }
    if (threadIdx.x == 0) off[n] = carry;
}

__global__ void scatter_edges(const int* __restrict__ ei, const int* __restrict__ et,
                              int* __restrict__ cursor, int* __restrict__ sorted, int E) {
    int e = blockIdx.x * blockDim.x + threadIdx.x;
    if (e >= E) return;
    int d = ei[E + e];
    int pos = atomicAdd(&cursor[d], 1);
    sorted[pos] = (ei[e] << 3) | et[e];   // pack src (<20000) and rel (<8)
}

// ---------------------------------------------------------------------------
// rel_proj = rel_emb @ rel_proj_w + b   ([8,256] @ [256,256])
// ---------------------------------------------------------------------------
__global__ void rel_proj_k(const float* __restrict__ rel_emb, const float* __restrict__ W,
                           const float* __restrict__ b, float* __restrict__ rel_proj) {
    int r = blockIdx.x;          // 8 blocks
    int j = threadIdx.x;         // 256 threads
    float acc = b[j];
    for (int i = 0; i < 256; ++i) acc += rel_emb[r * 256 + i] * W[i * 256 + j];
    rel_proj[r * 256 + j] = acc;
}

// rel_agg[n,:] = sum_r cnt[n,r] * rel_proj[r,:]
__global__ void rel_agg_k(const int* __restrict__ cnt, const float* __restrict__ rel_proj,
                          float* __restrict__ rel_agg) {
    int node = blockIdx.x;
    int j = threadIdx.x;
    float acc = 0.f;
#pragma unroll
    for (int r = 0; r < NREL; ++r)
        acc += (float)cnt[node * NREL + r] * rel_proj[r * 256 + j];
    rel_agg[(size_t)node * 256 + j] = acc;
}

// ---------------------------------------------------------------------------
// Fused GEMM: C = A[N,di] @ [Wrel (virtual [di, 8*do]) | Wroot [di,do]]
// writes hr [N, 8*do] and root [N, do]. fp32, 64x64x16 tiles, 256 thr, 4x4 micro.
// ---------------------------------------------------------------------------
#define BM 64
#define BN 64
#define BKK 16
__global__ __launch_bounds__(256) void gemm_virtual(
    const float* __restrict__ A, const float* __restrict__ Wrel,
    const float* __restrict__ Wroot, float* __restrict__ hr, float* __restrict__ root,
    int nrows, int di, int dout) {
    __shared__ float As[BKK][BM];
    __shared__ float Bs[BKK][BN];
    const int tid  = threadIdx.x;
    const int row0 = blockIdx.y * BM;
    const int col0 = blockIdx.x * BN;
    const int RD   = NREL * dout;
    const bool is_rel = (col0 < RD);
    const float* Bbase;
    if (is_rel) {
        int r = col0 / dout;
        Bbase = Wrel + (size_t)r * di * dout + (col0 - r * dout);
    } else {
        Bbase = Wroot + (col0 - RD);
    }
    const int arow  = tid >> 2;        // 0..63
    const int acol4 = (tid & 3) * 4;   // 0,4,8,12
    const int brow  = tid >> 4;        // 0..15
    const int bcol4 = (tid & 15) * 4;  // 0..60
    const int tx = tid & 15, ty = tid >> 4;
    float cacc[4][4] = {};
    for (int kk = 0; kk < di; kk += BKK) {
        float4 av = make_float4(0.f, 0.f, 0.f, 0.f);
        if (row0 + arow < nrows)
            av = *(const float4*)(A + (size_t)(row0 + arow) * di + kk + acol4);
        float4 bv = *(const float4*)(Bbase + (size_t)(kk + brow) * dout + bcol4);
        As[acol4 + 0][arow] = av.x;
        As[acol4 + 1][arow] = av.y;
        As[acol4 + 2][arow] = av.z;
        As[acol4 + 3][arow] = av.w;
        *(float4*)&Bs[brow][bcol4] = bv;
        __syncthreads();
#pragma unroll
        for (int k = 0; k < BKK; ++k) {
            float4 a = *(const float4*)&As[k][ty * 4];
            float4 b = *(const float4*)&Bs[k][tx * 4];
            float ar[4] = {a.x, a.y, a.z, a.w};
            float br[4] = {b.x, b.y, b.z, b.w};
#pragma unroll
            for (int i = 0; i < 4; ++i)
#pragma unroll
                for (int j = 0; j < 4; ++j) cacc[i][j] += ar[i] * br[j];
        }
        __syncthreads();
    }
    // store: whole block targets either hr or root
#pragma unroll
    for (int i = 0; i < 4; ++i) {
        int row = row0 + ty * 4 + i;
        if (row >= nrows) continue;
        float4 v0 = make_float4(cacc[i][0], cacc[i][1], cacc[i][2], cacc[i][3]);
        if (is_rel)
            *(float4*)(hr + (size_t)row * RD + col0 + tx * 4) = v0;
        else
            *(float4*)(root + (size_t)row * dout + (col0 - RD) + tx * 4) = v0;
    }
}

// ---------------------------------------------------------------------------
// s_src[n,r] = hr[n,r,:] . att_src ; s_dst[n] = root[n,:] . att_dst
// one wave per (node, idx), idx 0..8
// ---------------------------------------------------------------------------
template <int DO>
__global__ __launch_bounds__(256) void score_dots(
    const float* __restrict__ hr, const float* __restrict__ root,
    const float* __restrict__ att_src, const float* __restrict__ att_dst,
    float* __restrict__ s_src, float* __restrict__ s_dst, int n) {
    const int wg   = (blockIdx.x * blockDim.x + threadIdx.x) >> 6;
    const int lane = threadIdx.x & 63;
    if (wg >= n * 9) return;
    const int node = wg / 9;
    const int idx  = wg % 9;
    const float* vec;
    const float* att;
    if (idx < NREL) { vec = hr + (size_t)node * (NREL * DO) + idx * DO; att = att_src; }
    else            { vec = root + (size_t)node * DO;                    att = att_dst; }
    float acc = 0.f;
#pragma unroll
    for (int j = 0; j < DO / 64; ++j) acc += vec[j * 64 + lane] * att[j * 64 + lane];
    for (int o = 32; o > 0; o >>= 1) acc += __shfl_xor(acc, o);
    if (lane == 0) {
        if (idx < NREL) s_src[node * NREL + idx] = acc;
        else            s_dst[node] = acc;
    }
}

// ---------------------------------------------------------------------------
// Per-node segment softmax + weighted aggregation + layer epilogue.
// One wave per node. MODE 0: hidden (relu(out+rel_agg)+residual), 1: final.
// ---------------------------------------------------------------------------
template <int DO, int MODE>
__global__ __launch_bounds__(256) void attn_agg(
    const int* __restrict__ off, const int* __restrict__ sorted,
    const float* __restrict__ s_src, const float* __restrict__ s_dst,
    const float* __restrict__ hr, const float* __restrict__ root,
    const float* __restrict__ rel_agg, const float* __restrict__ h_prev,
    float* __restrict__ out, int n) {
    const int node = (blockIdx.x * blockDim.x + threadIdx.x) >> 6;
    const int lane = threadIdx.x & 63;
    if (node >= n) return;
    const int beg = off[node], end = off[node + 1];
    const int deg = end - beg;
    const float sdn = s_dst[node];
    constexpr int PER = DO / 64;
    float acc[PER];
#pragma unroll
    for (int j = 0; j < PER; ++j) acc[j] = 0.f;
    if (deg > 0) {
        float m = -1e30f;
        for (int e = lane; e < deg; e += 64) {
            int p = sorted[beg + e];
            float sc = s_src[(p >> 3) * NREL + (p & 7)] + sdn;
            sc = sc > 0.f ? sc : 0.2f * sc;
            m = fmaxf(m, sc);
        }
        for (int o = 32; o > 0; o >>= 1) m = fmaxf(m, __shfl_xor(m, o));
        float denom = 0.f;
        for (int e = 0; e < deg; ++e) {
            int p = sorted[beg + e];                       // wave-uniform broadcast
            float sc = s_src[(p >> 3) * NREL + (p & 7)] + sdn;
            sc = sc > 0.f ? sc : 0.2f * sc;
            float ex = expf(sc - m);
            denom += ex;
            const float* row = hr + (size_t)(p >> 3) * (NREL * DO) + (p & 7) * DO;
            if constexpr (PER == 4) {
                float4 v = *(const float4*)(row + lane * 4);
                acc[0] += ex * v.x; acc[1] += ex * v.y;
                acc[2] += ex * v.z; acc[3] += ex * v.w;
            } else {
                float2 v = *(const float2*)(row + lane * 2);
                acc[0] += ex * v.x; acc[1] += ex * v.y;
            }
        }
        float inv = 1.f / denom;
#pragma unroll
        for (int j = 0; j < PER; ++j) acc[j] *= inv;
    }
    const int cbase = lane * PER;
    if constexpr (MODE == 0) {
#pragma unroll
        for (int j = 0; j < PER; ++j) {
            int c = cbase + j;
            float r_ = root[(size_t)node * DO + c] + acc[j];
            float t  = r_ + rel_agg[(size_t)node * 256 + c];
            t = t > 0.f ? t : 0.f;
            out[(size_t)node * DO + c] = h_prev[(size_t)node * DO + c] + t;
        }
    } else {
#pragma unroll
        for (int j = 0; j < PER; ++j) {
            int c = cbase + j;
            out[(size_t)node * DO + c] = root[(size_t)node * DO + c] + acc[j];
        }
    }
}

// ---------------------------------------------------------------------------
extern "C" void kernel_launch(void* const* d_in, const int* in_sizes, int n_in,
                              void* d_out, int out_size, void* d_ws, size_t ws_size,
                              hipStream_t stream) {
    const int N = NNODES, E = NEDGES;
    const float* x        = (const float*)d_in[0];
    const int*   ei       = (const int*)d_in[1];
    const int*   et       = (const int*)d_in[2];
    const float* rel_emb  = (const float*)d_in[3];
    const float* rpw      = (const float*)d_in[4];
    const float* rpb      = (const float*)d_in[5];
    const float* Wrel0    = (const float*)d_in[6];
    const float* Wroot0   = (const float*)d_in[7];
    const float* asrc0    = (const float*)d_in[8];
    const float* adst0    = (const float*)d_in[9];
    const float* Wrel1    = (const float*)d_in[10];
    const float* Wroot1   = (const float*)d_in[11];
    const float* asrc1    = (const float*)d_in[12];
    const float* adst1    = (const float*)d_in[13];
    const float* Wrel2    = (const float*)d_in[14];
    const float* Wroot2   = (const float*)d_in[15];
    const float* asrc2    = (const float*)d_in[16];
    const float* adst2    = (const float*)d_in[17];
    float* outp = (float*)d_out;

    // workspace carve-up (256B aligned)
    char* w = (char*)d_ws;
    auto alloc = [&](size_t bytes) { char* p = w; w += (bytes + 255) & ~(size_t)255; return p; };
    float* hr      = (float*)alloc((size_t)N * 2048 * 4);
    float* root    = (float*)alloc((size_t)N * 256 * 4);
    float* h1      = (float*)alloc((size_t)N * 256 * 4);
    float* h2      = (float*)alloc((size_t)N * 256 * 4);
    float* relagg  = (float*)alloc((size_t)N * 256 * 4);
    float* relproj = (float*)alloc(NREL * 256 * 4);
    float* ssrc    = (float*)alloc((size_t)N * NREL * 4);
    float* sdst    = (float*)alloc((size_t)N * 4);
    int* deg       = (int*)alloc((size_t)N * 4);
    int* off       = (int*)alloc((size_t)(N + 1) * 4);
    int* cursor    = (int*)alloc((size_t)N * 4);
    int* relcnt    = (int*)alloc((size_t)N * NREL * 4);
    int* sorted    = (int*)alloc((size_t)E * 4);
    (void)ws_size; (void)in_sizes; (void)n_in; (void)out_size;

    hipMemsetAsync(deg, 0, (size_t)N * 4, stream);
    hipMemsetAsync(relcnt, 0, (size_t)N * NREL * 4, stream);

    const int EB = (E + 255) / 256;
    count_edges<<<EB, 256, 0, stream>>>(ei, et, deg, relcnt, E);
    scan_kernel<<<1, 1024, 0, stream>>>(deg, off, cursor, N);
    scatter_edges<<<EB, 256, 0, stream>>>(ei, et, cursor, sorted, E);
    rel_proj_k<<<NREL, 256, 0, stream>>>(rel_emb, rpw, rpb, relproj);
    rel_agg_k<<<N, 256, 0, stream>>>(relcnt, relproj, relagg);

    const int SSB = (N * 9 + 3) / 4;   // waves of 4 per block
    const int ATB = (N + 3) / 4;

    // layer 0: x -> h1
    {
        dim3 g((9 * 256) / BN, (N + BM - 1) / BM);
        gemm_virtual<<<g, 256, 0, stream>>>(x, Wrel0, Wroot0, hr, root, N, 256, 256);
        score_dots<256><<<SSB, 256, 0, stream>>>(hr, root, asrc0, adst0, ssrc, sdst, N);
        attn_agg<256, 0><<<ATB, 256, 0, stream>>>(off, sorted, ssrc, sdst, hr, root,
                                                  relagg, x, h1, N);
    }
    // layer 1: h1 -> h2
    {
        dim3 g((9 * 256) / BN, (N + BM - 1) / BM);
        gemm_virtual<<<g, 256, 0, stream>>>(h1, Wrel1, Wroot1, hr, root, N, 256, 256);
        score_dots<256><<<SSB, 256, 0, stream>>>(hr, root, asrc1, adst1, ssrc, sdst, N);
        attn_agg<256, 0><<<ATB, 256, 0, stream>>>(off, sorted, ssrc, sdst, hr, root,
                                                  relagg, h1, h2, N);
    }
    // layer 2: h2 -> out
    {
        dim3 g((9 * 128) / BN, (N + BM - 1) / BM);
        gemm_virtual<<<g, 256, 0, stream>>>(h2, Wrel2, Wroot2, hr, root, N, 256, 128);
        score_dots<128><<<SSB, 256, 0, stream>>>(hr, root, asrc2, adst2, ssrc, sdst, N);
        attn_agg<128, 1><<<ATB, 256, 0, stream>>>(off, sorted, ssrc, sdst, hr, root,
                                                  nullptr, nullptr, outp, N);
    }
}

// Round 4
// 820.015 us; speedup vs baseline: 1.6945x; 1.6945x over previous
//
#include <hip/hip_runtime.h>
#include <hip/hip_bf16.h>
#include <math.h>

#define NNODES 20000
#define NEDGES 400000
#define NREL 8

typedef __bf16 bf16_t;
typedef __bf16 bf16x8 __attribute__((ext_vector_type(8)));
typedef __bf16 bf16x4 __attribute__((ext_vector_type(4)));
typedef float f32x4 __attribute__((ext_vector_type(4)));

// ---------------------------------------------------------------------------
// Edge preprocessing
// ---------------------------------------------------------------------------
__global__ void count_edges(const int* __restrict__ ei, const int* __restrict__ et,
                            int* __restrict__ deg, int* __restrict__ rel_cnt, int E) {
    int e = blockIdx.x * blockDim.x + threadIdx.x;
    if (e >= E) return;
    int d = ei[E + e];
    atomicAdd(&deg[d], 1);
    atomicAdd(&rel_cnt[d * NREL + et[e]], 1);
}

// Single-block scan via wave shuffles.
__global__ void scan_kernel(const int* __restrict__ deg, int* __restrict__ off,
                            int* __restrict__ cursor, int n) {
    __shared__ int wsum[16];
    __shared__ int carry_s;
    const int lane = threadIdx.x & 63, wid = threadIdx.x >> 6;
    if (threadIdx.x == 0) carry_s = 0;
    __syncthreads();
    for (int base = 0; base < n; base += 1024) {
        int i = base + (int)threadIdx.x;
        int v = (i < n) ? deg[i] : 0;
        int s = v;
#pragma unroll
        for (int o = 1; o < 64; o <<= 1) {
            int t = __shfl_up(s, o);
            if (lane >= o) s += t;
        }
        if (lane == 63) wsum[wid] = s;
        __syncthreads();
        if (wid == 0) {
            int ws = (lane < 16) ? wsum[lane] : 0;
#pragma unroll
            for (int o = 1; o < 16; o <<= 1) {
                int t = __shfl_up(ws, o);
                if (lane >= o) ws += t;
            }
            if (lane < 16) wsum[lane] = ws;
        }
        __syncthreads();
        int wbase = (wid == 0) ? 0 : wsum[wid - 1];
        int excl = carry_s + wbase + s - v;
        if (i < n) { off[i] = excl; cursor[i] = excl; }
        __syncthreads();
        if (threadIdx.x == 0) carry_s += wsum[15];
        __syncthreads();
    }
    if (threadIdx.x == 0) off[n] = carry_s;
}

__global__ void scatter_edges(const int* __restrict__ ei, const int* __restrict__ et,
                              int* __restrict__ cursor, int* __restrict__ sorted, int E) {
    int e = blockIdx.x * blockDim.x + threadIdx.x;
    if (e >= E) return;
    int d = ei[E + e];
    int pos = atomicAdd(&cursor[d], 1);
    sorted[pos] = (ei[e] << 3) | et[e];
}

// ---------------------------------------------------------------------------
// rel_proj = rel_emb @ rel_proj_w + b  (tiny, [8,256]@[256,256])
// ---------------------------------------------------------------------------
__global__ void rel_proj_k(const float* __restrict__ rel_emb, const float* __restrict__ W,
                           const float* __restrict__ b, float* __restrict__ rel_proj) {
    int r = blockIdx.x, j = threadIdx.x;
    float acc = b[j];
    for (int i = 0; i < 256; ++i) acc += rel_emb[r * 256 + i] * W[i * 256 + j];
    rel_proj[r * 256 + j] = acc;
}

// ---------------------------------------------------------------------------
// fp32 -> split bf16 (hi + lo buffers; in == hi + lo up to ~2^-16 relative)
// ---------------------------------------------------------------------------
__global__ void cast_split(const float* __restrict__ in, bf16_t* __restrict__ hi_out,
                           bf16_t* __restrict__ lo_out, int n4) {
    int i = blockIdx.x * blockDim.x + threadIdx.x;
    if (i >= n4) return;
    float4 v = ((const float4*)in)[i];
    bf16x4 hi = {(bf16_t)v.x, (bf16_t)v.y, (bf16_t)v.z, (bf16_t)v.w};
    bf16x4 lo = {(bf16_t)(v.x - (float)hi.x), (bf16_t)(v.y - (float)hi.y),
                 (bf16_t)(v.z - (float)hi.z), (bf16_t)(v.w - (float)hi.w)};
    ((bf16x4*)hi_out)[i] = hi;
    ((bf16x4*)lo_out)[i] = lo;
}

// ---------------------------------------------------------------------------
// Pack virtual B = [Wrel | Wroot] as split-bf16 B-transposed [9*dout, 256] hi/lo
// ---------------------------------------------------------------------------
__global__ void pack_bt(const float* __restrict__ Wrel, const float* __restrict__ Wroot,
                        bf16_t* __restrict__ Bt_hi, bf16_t* __restrict__ Bt_lo,
                        int di, int dout) {
    int n = blockIdx.x, k = threadIdx.x;   // di = 256 threads
    int RD = NREL * dout;
    float v;
    if (n < RD) {
        int r = n / dout, j = n % dout;
        v = Wrel[(size_t)r * di * dout + (size_t)k * dout + j];
    } else {
        v = Wroot[(size_t)k * dout + (n - RD)];
    }
    bf16_t hi = (bf16_t)v;
    bf16_t lo = (bf16_t)(v - (float)hi);
    Bt_hi[(size_t)n * 256 + k] = hi;
    Bt_lo[(size_t)n * 256 + k] = lo;
}

// ---------------------------------------------------------------------------
// bf16 MFMA GEMM, split-bf16 3-pass: C = Ahi*Bhi + Ahi*Blo + Alo*Bhi
// (each pass K=256). 128x128 tile, BK=32, 4 waves, 4x4 16x16x32 frags,
// global_load_lds width 16, XOR chunk swizzle. fp32 C split into hr / root.
// ---------------------------------------------------------------------------
#define GBM 128
#define GBN 128
#define GBK 32

__global__ __launch_bounds__(256) void gemm_mfma(
    const bf16_t* __restrict__ Ahi, const bf16_t* __restrict__ Alo,
    const bf16_t* __restrict__ Bhi, const bf16_t* __restrict__ Blo,
    float* __restrict__ hr, float* __restrict__ root, int M, int dout) {
    constexpr int K = 256;
    const int RD = NREL * dout;
    __shared__ __align__(16) bf16_t As[GBM * GBK];
    __shared__ __align__(16) bf16_t Bs[GBN * GBK];
    const int tid  = threadIdx.x;
    const int lane = tid & 63;
    const int w    = tid >> 6;
    const int row0 = blockIdx.y * GBM;
    const int col0 = blockIdx.x * GBN;
    const int wm   = (w >> 1) * 64;
    const int wn   = (w & 1) * 64;

    f32x4 acc[4][4] = {};

    for (int pass = 0; pass < 3; ++pass) {
        const bf16_t* A = (pass == 2) ? Alo : Ahi;
        const bf16_t* B = (pass == 1) ? Blo : Bhi;
        for (int kb = 0; kb < K; kb += GBK) {
#pragma unroll
            for (int i = 0; i < 2; ++i) {
                int c  = i * 256 + tid;       // chunk id, 16B each
                int r  = c >> 2;              // tile row
                int cc = (c & 3) ^ (r & 3);   // swizzled k-chunk
                int ra = row0 + r; if (ra >= M) ra = M - 1;
                const bf16_t* ga = A + (size_t)ra * K + kb + cc * 8;
                __builtin_amdgcn_global_load_lds(
                    (const __attribute__((address_space(1))) void*)ga,
                    (__attribute__((address_space(3))) void*)(As + (size_t)c * 8), 16, 0, 0);
                const bf16_t* gb = B + (size_t)(col0 + r) * K + kb + cc * 8;
                __builtin_amdgcn_global_load_lds(
                    (const __attribute__((address_space(1))) void*)gb,
                    (__attribute__((address_space(3))) void*)(Bs + (size_t)c * 8), 16, 0, 0);
            }
            __syncthreads();

            const int q  = lane >> 4;            // k-chunk index 0..3
            const int sw = q ^ (lane & 3);       // swizzled chunk column
            bf16x8 af[4], bfr[4];
#pragma unroll
            for (int t = 0; t < 4; ++t) {
                int rr = wm + t * 16 + (lane & 15);
                af[t] = *(const bf16x8*)(As + rr * GBK + sw * 8);
                int rc = wn + t * 16 + (lane & 15);
                bfr[t] = *(const bf16x8*)(Bs + rc * GBK + sw * 8);
            }
#pragma unroll
            for (int mt = 0; mt < 4; ++mt)
#pragma unroll
                for (int nt = 0; nt < 4; ++nt)
                    acc[mt][nt] = __builtin_amdgcn_mfma_f32_16x16x32_bf16(
                        af[mt], bfr[nt], acc[mt][nt], 0, 0, 0);
            __syncthreads();
        }
    }

    const bool is_rel = (col0 < RD);
#pragma unroll
    for (int mt = 0; mt < 4; ++mt) {
#pragma unroll
        for (int reg = 0; reg < 4; ++reg) {
            int row = row0 + wm + mt * 16 + (lane >> 4) * 4 + reg;
            if (row >= M) continue;
#pragma unroll
            for (int nt = 0; nt < 4; ++nt) {
                int col = col0 + wn + nt * 16 + (lane & 15);
                float v = acc[mt][nt][reg];
                if (is_rel) hr[(size_t)row * RD + col] = v;
                else        root[(size_t)row * dout + (col - RD)] = v;
            }
        }
    }
}

// ---------------------------------------------------------------------------
// s_src[n,r] = hr[n,r,:].att_src ; s_dst[n] = root[n,:].att_dst
// ---------------------------------------------------------------------------
template <int DO>
__global__ __launch_bounds__(256) void score_dots(
    const float* __restrict__ hr, const float* __restrict__ root,
    const float* __restrict__ att_src, const float* __restrict__ att_dst,
    float* __restrict__ s_src, float* __restrict__ s_dst, int n) {
    const int wg   = (blockIdx.x * blockDim.x + threadIdx.x) >> 6;
    const int lane = threadIdx.x & 63;
    if (wg >= n * 9) return;
    const int node = wg / 9;
    const int idx  = wg % 9;
    const float* vec;
    const float* att;
    if (idx < NREL) { vec = hr + (size_t)node * (NREL * DO) + idx * DO; att = att_src; }
    else            { vec = root + (size_t)node * DO;                    att = att_dst; }
    float acc = 0.f;
#pragma unroll
    for (int j = 0; j < DO / 64; ++j) acc += vec[j * 64 + lane] * att[j * 64 + lane];
    for (int o = 32; o > 0; o >>= 1) acc += __shfl_xor(acc, o);
    if (lane == 0) {
        if (idx < NREL) s_src[node * NREL + idx] = acc;
        else            s_dst[node] = acc;
    }
}

// ---------------------------------------------------------------------------
// Segment softmax + aggregation + epilogue. One wave per node.
// MODE 0: out = h_prev + relu(root + agg + rel_agg), rel_agg computed on the
//         fly from relcnt x relproj (8 KB L2-resident table).
// MODE 1: out = root + agg.
// ---------------------------------------------------------------------------
template <int DO, int MODE>
__global__ __launch_bounds__(256) void attn_agg(
    const int* __restrict__ off, const int* __restrict__ sorted,
    const float* __restrict__ s_src, const float* __restrict__ s_dst,
    const float* __restrict__ hr, const float* __restrict__ root,
    const int* __restrict__ relcnt, const float* __restrict__ relproj,
    const float* __restrict__ h_prev, float* __restrict__ out, int n) {
    const int node = (blockIdx.x * blockDim.x + threadIdx.x) >> 6;
    const int lane = threadIdx.x & 63;
    if (node >= n) return;
    const int beg = off[node], end = off[node + 1];
    const int deg = end - beg;
    const float sdn = s_dst[node];
    constexpr int PER = DO / 64;
    float acc[PER];
#pragma unroll
    for (int j = 0; j < PER; ++j) acc[j] = 0.f;
    if (deg > 0) {
        float m = -1e30f;
        for (int e = lane; e < deg; e += 64) {
            int p = sorted[beg + e];
            float sc = s_src[(p >> 3) * NREL + (p & 7)] + sdn;
            sc = sc > 0.f ? sc : 0.2f * sc;
            m = fmaxf(m, sc);
        }
        for (int o = 32; o > 0; o >>= 1) m = fmaxf(m, __shfl_xor(m, o));
        float denom = 0.f;
        for (int e = 0; e < deg; ++e) {
            int p = sorted[beg + e];
            float sc = s_src[(p >> 3) * NREL + (p & 7)] + sdn;
            sc = sc > 0.f ? sc : 0.2f * sc;
            float ex = expf(sc - m);
            denom += ex;
            const float* row = hr + (size_t)(p >> 3) * (NREL * DO) + (p & 7) * DO;
            if constexpr (PER == 4) {
                float4 v = *(const float4*)(row + lane * 4);
                acc[0] += ex * v.x; acc[1] += ex * v.y;
                acc[2] += ex * v.z; acc[3] += ex * v.w;
            } else {
                float2 v = *(const float2*)(row + lane * 2);
                acc[0] += ex * v.x; acc[1] += ex * v.y;
            }
        }
        float inv = 1.f / denom;
#pragma unroll
        for (int j = 0; j < PER; ++j) acc[j] *= inv;
    }
    const int cbase = lane * PER;
    if constexpr (MODE == 0) {
        float rsum[PER];
#pragma unroll
        for (int j = 0; j < PER; ++j) rsum[j] = 0.f;
#pragma unroll
        for (int r = 0; r < NREL; ++r) {
            float cr = (float)relcnt[node * NREL + r];
            const float* rp = relproj + r * 256 + cbase;
#pragma unroll
            for (int j = 0; j < PER; ++j) rsum[j] += cr * rp[j];
        }
#pragma unroll
        for (int j = 0; j < PER; ++j) {
            int c = cbase + j;
            float r_ = root[(size_t)node * DO + c] + acc[j];
            float t  = r_ + rsum[j];
            t = t > 0.f ? t : 0.f;
            out[(size_t)node * DO + c] = h_prev[(size_t)node * DO + c] + t;
        }
    } else {
#pragma unroll
        for (int j = 0; j < PER; ++j) {
            int c = cbase + j;
            out[(size_t)node * DO + c] = root[(size_t)node * DO + c] + acc[j];
        }
    }
}

// ---------------------------------------------------------------------------
extern "C" void kernel_launch(void* const* d_in, const int* in_sizes, int n_in,
                              void* d_out, int out_size, void* d_ws, size_t ws_size,
                              hipStream_t stream) {
    const int N = NNODES, E = NEDGES;
    const float* x        = (const float*)d_in[0];
    const int*   ei       = (const int*)d_in[1];
    const int*   et       = (const int*)d_in[2];
    const float* rel_emb  = (const float*)d_in[3];
    const float* rpw      = (const float*)d_in[4];
    const float* rpb      = (const float*)d_in[5];
    const float* Wrel0    = (const float*)d_in[6];
    const float* Wroot0   = (const float*)d_in[7];
    const float* asrc0    = (const float*)d_in[8];
    const float* adst0    = (const float*)d_in[9];
    const float* Wrel1    = (const float*)d_in[10];
    const float* Wroot1   = (const float*)d_in[11];
    const float* asrc1    = (const float*)d_in[12];
    const float* adst1    = (const float*)d_in[13];
    const float* Wrel2    = (const float*)d_in[14];
    const float* Wroot2   = (const float*)d_in[15];
    const float* asrc2    = (const float*)d_in[16];
    const float* adst2    = (const float*)d_in[17];
    float* outp = (float*)d_out;

    // Workspace budget: 256 MiB (R3 crashed at 270 MiB). This layout: ~240 MiB.
    char* w = (char*)d_ws;
    auto alloc = [&](size_t bytes) { char* p = w; w += (bytes + 255) & ~(size_t)255; return p; };
    float* hr      = (float*)alloc((size_t)N * 2048 * 4);   // 163.8 MB
    float* root    = (float*)alloc((size_t)N * 256 * 4);    // 20.5 MB
    float* h1      = (float*)alloc((size_t)N * 256 * 4);    // 20.5 MB
    float* h2      = (float*)alloc((size_t)N * 256 * 4);    // 20.5 MB
    float* relproj = (float*)alloc(NREL * 256 * 4);
    float* ssrc    = (float*)alloc((size_t)N * NREL * 4);
    float* sdst    = (float*)alloc((size_t)N * 4);
    bf16_t* hAhi   = (bf16_t*)alloc((size_t)N * 256 * 2);   // 10.2 MB
    bf16_t* hAlo   = (bf16_t*)alloc((size_t)N * 256 * 2);   // 10.2 MB
    bf16_t* Bthi   = (bf16_t*)alloc((size_t)2304 * 256 * 2);
    bf16_t* Btlo   = (bf16_t*)alloc((size_t)2304 * 256 * 2);
    int* deg       = (int*)alloc((size_t)N * 4);
    int* off       = (int*)alloc((size_t)(N + 1) * 4);
    int* cursor    = (int*)alloc((size_t)N * 4);
    int* relcnt    = (int*)alloc((size_t)N * NREL * 4);
    int* sorted    = (int*)alloc((size_t)E * 4);
    (void)ws_size; (void)in_sizes; (void)n_in; (void)out_size;

    hipMemsetAsync(deg, 0, (size_t)N * 4, stream);
    hipMemsetAsync(relcnt, 0, (size_t)N * NREL * 4, stream);

    const int EB = (E + 255) / 256;
    count_edges<<<EB, 256, 0, stream>>>(ei, et, deg, relcnt, E);
    scan_kernel<<<1, 1024, 0, stream>>>(deg, off, cursor, N);
    scatter_edges<<<EB, 256, 0, stream>>>(ei, et, cursor, sorted, E);
    rel_proj_k<<<NREL, 256, 0, stream>>>(rel_emb, rpw, rpb, relproj);

    const int SSB = (N * 9 + 3) / 4;
    const int ATB = (N + 3) / 4;
    const int CB  = (N * 64 + 255) / 256;   // N*256/4 float4 groups
    const int MB  = (N + GBM - 1) / GBM;    // 157

    // layer 0: x -> h1
    cast_split<<<CB, 256, 0, stream>>>(x, hAhi, hAlo, N * 64);
    pack_bt<<<2304, 256, 0, stream>>>(Wrel0, Wroot0, Bthi, Btlo, 256, 256);
    {
        dim3 g(2304 / GBN, MB);
        gemm_mfma<<<g, 256, 0, stream>>>(hAhi, hAlo, Bthi, Btlo, hr, root, N, 256);
    }
    score_dots<256><<<SSB, 256, 0, stream>>>(hr, root, asrc0, adst0, ssrc, sdst, N);
    attn_agg<256, 0><<<ATB, 256, 0, stream>>>(off, sorted, ssrc, sdst, hr, root,
                                              relcnt, relproj, x, h1, N);
    // layer 1: h1 -> h2
    cast_split<<<CB, 256, 0, stream>>>(h1, hAhi, hAlo, N * 64);
    pack_bt<<<2304, 256, 0, stream>>>(Wrel1, Wroot1, Bthi, Btlo, 256, 256);
    {
        dim3 g(2304 / GBN, MB);
        gemm_mfma<<<g, 256, 0, stream>>>(hAhi, hAlo, Bthi, Btlo, hr, root, N, 256);
    }
    score_dots<256><<<SSB, 256, 0, stream>>>(hr, root, asrc1, adst1, ssrc, sdst, N);
    attn_agg<256, 0><<<ATB, 256, 0, stream>>>(off, sorted, ssrc, sdst, hr, root,
                                              relcnt, relproj, h1, h2, N);
    // layer 2: h2 -> out
    cast_split<<<CB, 256, 0, stream>>>(h2, hAhi, hAlo, N * 64);
    pack_bt<<<1152, 256, 0, stream>>>(Wrel2, Wroot2, Bthi, Btlo, 256, 128);
    {
        dim3 g(1152 / GBN, MB);
        gemm_mfma<<<g, 256, 0, stream>>>(hAhi, hAlo, Bthi, Btlo, hr, root, N, 128);
    }
    score_dots<128><<<SSB, 256, 0, stream>>>(hr, root, asrc2, adst2, ssrc, sdst, N);
    attn_agg<128, 1><<<ATB, 256, 0, stream>>>(off, sorted, ssrc, sdst, hr, root,
                                              nullptr, nullptr, nullptr, outp, N);
}

// Round 5
// 691.728 us; speedup vs baseline: 2.0088x; 1.1855x over previous
//
#include <hip/hip_runtime.h>
#include <hip/hip_bf16.h>
#include <math.h>

#define NNODES 20000
#define NEDGES 400000
#define NREL 8

typedef __bf16 bf16_t;
typedef __bf16 bf16x8 __attribute__((ext_vector_type(8)));
typedef __bf16 bf16x4 __attribute__((ext_vector_type(4)));
typedef __bf16 bf16x2 __attribute__((ext_vector_type(2)));
typedef float f32x4 __attribute__((ext_vector_type(4)));

// ---------------------------------------------------------------------------
// Edge preprocessing
// ---------------------------------------------------------------------------
__global__ void count_edges(const int* __restrict__ ei, const int* __restrict__ et,
                            int* __restrict__ deg, int* __restrict__ rel_cnt, int E) {
    int e = blockIdx.x * blockDim.x + threadIdx.x;
    if (e >= E) return;
    int d = ei[E + e];
    atomicAdd(&deg[d], 1);
    atomicAdd(&rel_cnt[d * NREL + et[e]], 1);
}

__global__ void scan_kernel(const int* __restrict__ deg, int* __restrict__ off,
                            int* __restrict__ cursor, int n) {
    __shared__ int wsum[16];
    __shared__ int carry_s;
    const int lane = threadIdx.x & 63, wid = threadIdx.x >> 6;
    if (threadIdx.x == 0) carry_s = 0;
    __syncthreads();
    for (int base = 0; base < n; base += 1024) {
        int i = base + (int)threadIdx.x;
        int v = (i < n) ? deg[i] : 0;
        int s = v;
#pragma unroll
        for (int o = 1; o < 64; o <<= 1) {
            int t = __shfl_up(s, o);
            if (lane >= o) s += t;
        }
        if (lane == 63) wsum[wid] = s;
        __syncthreads();
        if (wid == 0) {
            int ws = (lane < 16) ? wsum[lane] : 0;
#pragma unroll
            for (int o = 1; o < 16; o <<= 1) {
                int t = __shfl_up(ws, o);
                if (lane >= o) ws += t;
            }
            if (lane < 16) wsum[lane] = ws;
        }
        __syncthreads();
        int wbase = (wid == 0) ? 0 : wsum[wid - 1];
        int excl = carry_s + wbase + s - v;
        if (i < n) { off[i] = excl; cursor[i] = excl; }
        __syncthreads();
        if (threadIdx.x == 0) carry_s += wsum[15];
        __syncthreads();
    }
    if (threadIdx.x == 0) off[n] = carry_s;
}

__global__ void scatter_edges(const int* __restrict__ ei, const int* __restrict__ et,
                              int* __restrict__ cursor, int* __restrict__ sorted, int E) {
    int e = blockIdx.x * blockDim.x + threadIdx.x;
    if (e >= E) return;
    int d = ei[E + e];
    int pos = atomicAdd(&cursor[d], 1);
    sorted[pos] = (ei[e] << 3) | et[e];
}

// ---------------------------------------------------------------------------
// rel_proj = rel_emb @ rel_proj_w + b  (tiny)
// ---------------------------------------------------------------------------
__global__ void rel_proj_k(const float* __restrict__ rel_emb, const float* __restrict__ W,
                           const float* __restrict__ b, float* __restrict__ rel_proj) {
    int r = blockIdx.x, j = threadIdx.x;
    float acc = b[j];
    for (int i = 0; i < 256; ++i) acc += rel_emb[r * 256 + i] * W[i * 256 + j];
    rel_proj[r * 256 + j] = acc;
}

// ---------------------------------------------------------------------------
// watt[idx][k]: idx<8 -> Wrel_r @ att_src column-dots; idx==8 -> Wroot @ att_dst.
// s_src[n,r] = h[n]·watt[r]  (identical to (h@Wrel_r)·att_src by associativity)
// ---------------------------------------------------------------------------
__global__ __launch_bounds__(256) void watt_k(
    const float* __restrict__ Wrel, const float* __restrict__ Wroot,
    const float* __restrict__ att_src, const float* __restrict__ att_dst,
    float* __restrict__ watt, int dout) {
    const int wg = (blockIdx.x * blockDim.x + threadIdx.x) >> 6;
    const int lane = threadIdx.x & 63;
    if (wg >= 9 * 256) return;
    const int idx = wg >> 8, k = wg & 255;
    float a = 0.f;
    if (idx < NREL) {
        const float* wrow = Wrel + ((size_t)idx * 256 + k) * dout;
        for (int j = lane; j < dout; j += 64) a += wrow[j] * att_src[j];
    } else {
        const float* wrow = Wroot + (size_t)k * dout;
        for (int j = lane; j < dout; j += 64) a += wrow[j] * att_dst[j];
    }
    for (int o = 32; o > 0; o >>= 1) a += __shfl_xor(a, o);
    if (lane == 0) watt[idx * 256 + k] = a;
}

// ---------------------------------------------------------------------------
// Fused: split-cast h into A2=[hi|lo] (K=512 layout) + 9 attention dots.
// One wave per node; reads h exactly once.
// ---------------------------------------------------------------------------
__global__ __launch_bounds__(256) void cast_score(
    const float* __restrict__ h, const float* __restrict__ watt,
    bf16_t* __restrict__ A2, float* __restrict__ s_src, float* __restrict__ s_dst, int n) {
    const int node = (blockIdx.x * blockDim.x + threadIdx.x) >> 6;
    const int lane = threadIdx.x & 63;
    if (node >= n) return;
    float4 v = *(const float4*)(h + (size_t)node * 256 + lane * 4);
    bf16x4 hi = {(bf16_t)v.x, (bf16_t)v.y, (bf16_t)v.z, (bf16_t)v.w};
    bf16x4 lo = {(bf16_t)(v.x - (float)hi[0]), (bf16_t)(v.y - (float)hi[1]),
                 (bf16_t)(v.z - (float)hi[2]), (bf16_t)(v.w - (float)hi[3])};
    *(bf16x4*)(A2 + (size_t)node * 512 + lane * 4)       = hi;
    *(bf16x4*)(A2 + (size_t)node * 512 + 256 + lane * 4) = lo;
#pragma unroll
    for (int idx = 0; idx < 9; ++idx) {
        const float* wv = watt + idx * 256 + lane * 4;
        float a = v.x * wv[0] + v.y * wv[1] + v.z * wv[2] + v.w * wv[3];
        for (int o = 32; o > 0; o >>= 1) a += __shfl_xor(a, o);
        if (lane == 0) {
            if (idx < NREL) s_src[node * NREL + idx] = a;
            else            s_dst[node] = a;
        }
    }
}

// ---------------------------------------------------------------------------
// Pack B2 = [Wrel | Wroot]^T in split layout [9*dout, 512]: [:,0:256]=hi, [:,256:512]=lo
// ---------------------------------------------------------------------------
__global__ void pack_bt(const float* __restrict__ Wrel, const float* __restrict__ Wroot,
                        bf16_t* __restrict__ B2, int di, int dout) {
    int n = blockIdx.x, k = threadIdx.x;
    int RD = NREL * dout;
    float v;
    if (n < RD) {
        int r = n / dout, j = n % dout;
        v = Wrel[(size_t)r * di * dout + (size_t)k * dout + j];
    } else {
        v = Wroot[(size_t)k * dout + (n - RD)];
    }
    bf16_t hi = (bf16_t)v;
    bf16_t lo = (bf16_t)(v - (float)hi);
    B2[(size_t)n * 512 + k]       = hi;
    B2[(size_t)n * 512 + 256 + k] = lo;
}

// ---------------------------------------------------------------------------
// Split-bf16 full-product GEMM (K=512): C = (Ahi+Alo)(Bhi+Blo) ~ fp32 exact.
// 128x128 tile, BK=32, 4 waves, 4x4 16x16x32 frags, global_load_lds width 16.
// LDS swizzle period-16 ((r>>2)&3) -> 2-way bank aliasing only (free, m136).
// hr written bf16 (82 MB, L3-resident); root fp32.
// ---------------------------------------------------------------------------
#define GBM 128
#define GBN 128
#define GBK 32

__global__ __launch_bounds__(256) void gemm_mfma(
    const bf16_t* __restrict__ A2, const bf16_t* __restrict__ B2,
    bf16_t* __restrict__ hrb, float* __restrict__ root, int M, int dout) {
    constexpr int K = 512;
    const int RD = NREL * dout;
    __shared__ __align__(16) bf16_t As[GBM * GBK];
    __shared__ __align__(16) bf16_t Bs[GBN * GBK];
    const int tid  = threadIdx.x;
    const int lane = tid & 63;
    const int w    = tid >> 6;
    const int row0 = blockIdx.y * GBM;
    const int col0 = blockIdx.x * GBN;
    const int wm   = (w >> 1) * 64;
    const int wn   = (w & 1) * 64;

    f32x4 acc[4][4] = {};

    for (int kb = 0; kb < K; kb += GBK) {
#pragma unroll
        for (int i = 0; i < 2; ++i) {
            int c  = i * 256 + tid;            // chunk id, 16B each (512 per tile)
            int r  = c >> 2;                   // tile row
            int cc = (c & 3) ^ ((r >> 2) & 3); // period-16 swizzle
            int ra = row0 + r; if (ra >= M) ra = M - 1;
            const bf16_t* ga = A2 + (size_t)ra * K + kb + cc * 8;
            __builtin_amdgcn_global_load_lds(
                (const __attribute__((address_space(1))) void*)ga,
                (__attribute__((address_space(3))) void*)(As + (size_t)c * 8), 16, 0, 0);
            const bf16_t* gb = B2 + (size_t)(col0 + r) * K + kb + cc * 8;
            __builtin_amdgcn_global_load_lds(
                (const __attribute__((address_space(1))) void*)gb,
                (__attribute__((address_space(3))) void*)(Bs + (size_t)c * 8), 16, 0, 0);
        }
        __syncthreads();

        const int q  = lane >> 4;              // wanted k-chunk
        const int sw = q ^ ((lane >> 2) & 3);  // swizzled slot ((rr>>2)&3 == (lane>>2)&3)
        bf16x8 af[4], bfr[4];
#pragma unroll
        for (int t = 0; t < 4; ++t) {
            int rr = wm + t * 16 + (lane & 15);
            af[t] = *(const bf16x8*)(As + rr * GBK + sw * 8);
            int rc = wn + t * 16 + (lane & 15);
            bfr[t] = *(const bf16x8*)(Bs + rc * GBK + sw * 8);
        }
#pragma unroll
        for (int mt = 0; mt < 4; ++mt)
#pragma unroll
            for (int nt = 0; nt < 4; ++nt)
                acc[mt][nt] = __builtin_amdgcn_mfma_f32_16x16x32_bf16(
                    af[mt], bfr[nt], acc[mt][nt], 0, 0, 0);
        __syncthreads();
    }

    const bool is_rel = (col0 < RD);
#pragma unroll
    for (int mt = 0; mt < 4; ++mt) {
#pragma unroll
        for (int reg = 0; reg < 4; ++reg) {
            int row = row0 + wm + mt * 16 + (lane >> 4) * 4 + reg;
            if (row >= M) continue;
#pragma unroll
            for (int nt = 0; nt < 4; ++nt) {
                int col = col0 + wn + nt * 16 + (lane & 15);
                float v = acc[mt][nt][reg];
                if (is_rel) hrb[(size_t)row * RD + col] = (bf16_t)v;
                else        root[(size_t)row * dout + (col - RD)] = v;
            }
        }
    }
}

// ---------------------------------------------------------------------------
// Segment softmax + aggregation + epilogue. One wave per node. hr rows bf16.
// MODE 0: out = h_prev + relu(root + agg + rel_agg(on-the-fly)); MODE 1: root+agg.
// ---------------------------------------------------------------------------
template <int DO, int MODE>
__global__ __launch_bounds__(256) void attn_agg(
    const int* __restrict__ off, const int* __restrict__ sorted,
    const float* __restrict__ s_src, const float* __restrict__ s_dst,
    const bf16_t* __restrict__ hrb, const float* __restrict__ root,
    const int* __restrict__ relcnt, const float* __restrict__ relproj,
    const float* __restrict__ h_prev, float* __restrict__ out, int n) {
    const int node = (blockIdx.x * blockDim.x + threadIdx.x) >> 6;
    const int lane = threadIdx.x & 63;
    if (node >= n) return;
    const int beg = off[node], end = off[node + 1];
    const int deg = end - beg;
    const float sdn = s_dst[node];
    constexpr int PER = DO / 64;
    float acc[PER];
#pragma unroll
    for (int j = 0; j < PER; ++j) acc[j] = 0.f;
    if (deg > 0) {
        float m = -1e30f;
        for (int e = lane; e < deg; e += 64) {
            int p = sorted[beg + e];
            float sc = s_src[(p >> 3) * NREL + (p & 7)] + sdn;
            sc = sc > 0.f ? sc : 0.2f * sc;
            m = fmaxf(m, sc);
        }
        for (int o = 32; o > 0; o >>= 1) m = fmaxf(m, __shfl_xor(m, o));
        float denom = 0.f;
        for (int e = 0; e < deg; ++e) {
            int p = sorted[beg + e];
            float sc = s_src[(p >> 3) * NREL + (p & 7)] + sdn;
            sc = sc > 0.f ? sc : 0.2f * sc;
            float ex = expf(sc - m);
            denom += ex;
            const bf16_t* row = hrb + (size_t)(p >> 3) * (NREL * DO) + (p & 7) * DO;
            if constexpr (PER == 4) {
                bf16x4 v = *(const bf16x4*)(row + lane * 4);
                acc[0] += ex * (float)v[0]; acc[1] += ex * (float)v[1];
                acc[2] += ex * (float)v[2]; acc[3] += ex * (float)v[3];
            } else {
                bf16x2 v = *(const bf16x2*)(row + lane * 2);
                acc[0] += ex * (float)v[0]; acc[1] += ex * (float)v[1];
            }
        }
        float inv = 1.f / denom;
#pragma unroll
        for (int j = 0; j < PER; ++j) acc[j] *= inv;
    }
    const int cbase = lane * PER;
    if constexpr (MODE == 0) {
        float rsum[PER];
#pragma unroll
        for (int j = 0; j < PER; ++j) rsum[j] = 0.f;
#pragma unroll
        for (int r = 0; r < NREL; ++r) {
            float cr = (float)relcnt[node * NREL + r];
            const float* rp = relproj + r * 256 + cbase;
#pragma unroll
            for (int j = 0; j < PER; ++j) rsum[j] += cr * rp[j];
        }
#pragma unroll
        for (int j = 0; j < PER; ++j) {
            int c = cbase + j;
            float r_ = root[(size_t)node * DO + c] + acc[j];
            float t  = r_ + rsum[j];
            t = t > 0.f ? t : 0.f;
            out[(size_t)node * DO + c] = h_prev[(size_t)node * DO + c] + t;
        }
    } else {
#pragma unroll
        for (int j = 0; j < PER; ++j) {
            int c = cbase + j;
            out[(size_t)node * DO + c] = root[(size_t)node * DO + c] + acc[j];
        }
    }
}

// ---------------------------------------------------------------------------
extern "C" void kernel_launch(void* const* d_in, const int* in_sizes, int n_in,
                              void* d_out, int out_size, void* d_ws, size_t ws_size,
                              hipStream_t stream) {
    const int N = NNODES, E = NEDGES;
    const float* x        = (const float*)d_in[0];
    const int*   ei       = (const int*)d_in[1];
    const int*   et       = (const int*)d_in[2];
    const float* rel_emb  = (const float*)d_in[3];
    const float* rpw      = (const float*)d_in[4];
    const float* rpb      = (const float*)d_in[5];
    const float* Wrel0    = (const float*)d_in[6];
    const float* Wroot0   = (const float*)d_in[7];
    const float* asrc0    = (const float*)d_in[8];
    const float* adst0    = (const float*)d_in[9];
    const float* Wrel1    = (const float*)d_in[10];
    const float* Wroot1   = (const float*)d_in[11];
    const float* asrc1    = (const float*)d_in[12];
    const float* adst1    = (const float*)d_in[13];
    const float* Wrel2    = (const float*)d_in[14];
    const float* Wroot2   = (const float*)d_in[15];
    const float* asrc2    = (const float*)d_in[16];
    const float* adst2    = (const float*)d_in[17];
    float* outp = (float*)d_out;

    // Workspace ~170 MB of 256 MiB budget.
    char* w = (char*)d_ws;
    auto alloc = [&](size_t bytes) { char* p = w; w += (bytes + 255) & ~(size_t)255; return p; };
    bf16_t* hrb    = (bf16_t*)alloc((size_t)N * 2048 * 2);  // 81.9 MB
    float* root    = (float*)alloc((size_t)N * 256 * 4);    // 20.5 MB
    float* h1      = (float*)alloc((size_t)N * 256 * 4);
    float* h2      = (float*)alloc((size_t)N * 256 * 4);
    float* relproj = (float*)alloc(NREL * 256 * 4);
    float* watt    = (float*)alloc(9 * 256 * 4);
    float* ssrc    = (float*)alloc((size_t)N * NREL * 4);
    float* sdst    = (float*)alloc((size_t)N * 4);
    bf16_t* A2     = (bf16_t*)alloc((size_t)N * 512 * 2);   // 20.5 MB
    bf16_t* B2     = (bf16_t*)alloc((size_t)2304 * 512 * 2);
    int* deg       = (int*)alloc((size_t)N * 4);
    int* off       = (int*)alloc((size_t)(N + 1) * 4);
    int* cursor    = (int*)alloc((size_t)N * 4);
    int* relcnt    = (int*)alloc((size_t)N * NREL * 4);
    int* sorted    = (int*)alloc((size_t)E * 4);
    (void)ws_size; (void)in_sizes; (void)n_in; (void)out_size;

    hipMemsetAsync(deg, 0, (size_t)N * 4, stream);
    hipMemsetAsync(relcnt, 0, (size_t)N * NREL * 4, stream);

    const int EB = (E + 255) / 256;
    count_edges<<<EB, 256, 0, stream>>>(ei, et, deg, relcnt, E);
    scan_kernel<<<1, 1024, 0, stream>>>(deg, off, cursor, N);
    scatter_edges<<<EB, 256, 0, stream>>>(ei, et, cursor, sorted, E);
    rel_proj_k<<<NREL, 256, 0, stream>>>(rel_emb, rpw, rpb, relproj);

    const int ATB = (N + 3) / 4;           // attn_agg / cast_score: 4 waves/block
    const int WB  = (9 * 256) / 4;         // watt_k waves /4
    const int MB  = (N + GBM - 1) / GBM;   // 157

    // layer 0: x -> h1
    watt_k<<<WB, 256, 0, stream>>>(Wrel0, Wroot0, asrc0, adst0, watt, 256);
    cast_score<<<ATB, 256, 0, stream>>>(x, watt, A2, ssrc, sdst, N);
    pack_bt<<<2304, 256, 0, stream>>>(Wrel0, Wroot0, B2, 256, 256);
    { dim3 g(2304 / GBN, MB);
      gemm_mfma<<<g, 256, 0, stream>>>(A2, B2, hrb, root, N, 256); }
    attn_agg<256, 0><<<ATB, 256, 0, stream>>>(off, sorted, ssrc, sdst, hrb, root,
                                              relcnt, relproj, x, h1, N);
    // layer 1: h1 -> h2
    watt_k<<<WB, 256, 0, stream>>>(Wrel1, Wroot1, asrc1, adst1, watt, 256);
    cast_score<<<ATB, 256, 0, stream>>>(h1, watt, A2, ssrc, sdst, N);
    pack_bt<<<2304, 256, 0, stream>>>(Wrel1, Wroot1, B2, 256, 256);
    { dim3 g(2304 / GBN, MB);
      gemm_mfma<<<g, 256, 0, stream>>>(A2, B2, hrb, root, N, 256); }
    attn_agg<256, 0><<<ATB, 256, 0, stream>>>(off, sorted, ssrc, sdst, hrb, root,
                                              relcnt, relproj, h1, h2, N);
    // layer 2: h2 -> out
    watt_k<<<WB, 256, 0, stream>>>(Wrel2, Wroot2, asrc2, adst2, watt, 128);
    cast_score<<<ATB, 256, 0, stream>>>(h2, watt, A2, ssrc, sdst, N);
    pack_bt<<<1152, 256, 0, stream>>>(Wrel2, Wroot2, B2, 256, 128);
    { dim3 g(1152 / GBN, MB);
      gemm_mfma<<<g, 256, 0, stream>>>(A2, B2, hrb, root, N, 128); }
    attn_agg<128, 1><<<ATB, 256, 0, stream>>>(off, sorted, ssrc, sdst, hrb, root,
                                              nullptr, nullptr, nullptr, outp, N);
}

// Round 6
// 587.777 us; speedup vs baseline: 2.3640x; 1.1769x over previous
//
#include <hip/hip_runtime.h>
#include <hip/hip_bf16.h>
#include <math.h>

#define NNODES 20000
#define NEDGES 400000
#define NREL 8

typedef __bf16 bf16_t;
typedef __bf16 bf16x8 __attribute__((ext_vector_type(8)));
typedef __bf16 bf16x4 __attribute__((ext_vector_type(4)));
typedef _Float16 h16x4 __attribute__((ext_vector_type(4)));
typedef _Float16 h16x2 __attribute__((ext_vector_type(2)));
typedef float f32x4 __attribute__((ext_vector_type(4)));

// ---------------------------------------------------------------------------
// Edge preprocessing
// ---------------------------------------------------------------------------
__global__ void count_edges(const int* __restrict__ ei, const int* __restrict__ et,
                            int* __restrict__ deg, int* __restrict__ rel_cnt, int E) {
    int e = blockIdx.x * blockDim.x + threadIdx.x;
    if (e >= E) return;
    int d = ei[E + e];
    atomicAdd(&deg[d], 1);
    atomicAdd(&rel_cnt[d * NREL + et[e]], 1);
}

__global__ void scan_kernel(const int* __restrict__ deg, int* __restrict__ off,
                            int* __restrict__ cursor, int n) {
    __shared__ int wsum[16];
    __shared__ int carry_s;
    const int lane = threadIdx.x & 63, wid = threadIdx.x >> 6;
    if (threadIdx.x == 0) carry_s = 0;
    __syncthreads();
    for (int base = 0; base < n; base += 1024) {
        int i = base + (int)threadIdx.x;
        int v = (i < n) ? deg[i] : 0;
        int s = v;
#pragma unroll
        for (int o = 1; o < 64; o <<= 1) {
            int t = __shfl_up(s, o);
            if (lane >= o) s += t;
        }
        if (lane == 63) wsum[wid] = s;
        __syncthreads();
        if (wid == 0) {
            int ws = (lane < 16) ? wsum[lane] : 0;
#pragma unroll
            for (int o = 1; o < 16; o <<= 1) {
                int t = __shfl_up(ws, o);
                if (lane >= o) ws += t;
            }
            if (lane < 16) wsum[lane] = ws;
        }
        __syncthreads();
        int wbase = (wid == 0) ? 0 : wsum[wid - 1];
        int excl = carry_s + wbase + s - v;
        if (i < n) { off[i] = excl; cursor[i] = excl; }
        __syncthreads();
        if (threadIdx.x == 0) carry_s += wsum[15];
        __syncthreads();
    }
    if (threadIdx.x == 0) off[n] = carry_s;
}

__global__ void scatter_edges(const int* __restrict__ ei, const int* __restrict__ et,
                              int* __restrict__ cursor, int* __restrict__ sorted, int E) {
    int e = blockIdx.x * blockDim.x + threadIdx.x;
    if (e >= E) return;
    int d = ei[E + e];
    int pos = atomicAdd(&cursor[d], 1);
    sorted[pos] = (ei[e] << 3) | et[e];
}

// ---------------------------------------------------------------------------
// rel_proj = rel_emb @ rel_proj_w + b  (tiny)
// ---------------------------------------------------------------------------
__global__ void rel_proj_k(const float* __restrict__ rel_emb, const float* __restrict__ W,
                           const float* __restrict__ b, float* __restrict__ rel_proj) {
    int r = blockIdx.x, j = threadIdx.x;
    float acc = b[j];
    for (int i = 0; i < 256; ++i) acc += rel_emb[r * 256 + i] * W[i * 256 + j];
    rel_proj[r * 256 + j] = acc;
}

// ---------------------------------------------------------------------------
// watt[idx][k]: idx<8 -> Wrel_r @ att_src; idx==8 -> Wroot @ att_dst.
// ---------------------------------------------------------------------------
__global__ __launch_bounds__(256) void watt_k(
    const float* __restrict__ Wrel, const float* __restrict__ Wroot,
    const float* __restrict__ att_src, const float* __restrict__ att_dst,
    float* __restrict__ watt, int dout) {
    const int wg = (blockIdx.x * blockDim.x + threadIdx.x) >> 6;
    const int lane = threadIdx.x & 63;
    if (wg >= 9 * 256) return;
    const int idx = wg >> 8, k = wg & 255;
    float a = 0.f;
    if (idx < NREL) {
        const float* wrow = Wrel + ((size_t)idx * 256 + k) * dout;
        for (int j = lane; j < dout; j += 64) a += wrow[j] * att_src[j];
    } else {
        const float* wrow = Wroot + (size_t)k * dout;
        for (int j = lane; j < dout; j += 64) a += wrow[j] * att_dst[j];
    }
    for (int o = 32; o > 0; o >>= 1) a += __shfl_xor(a, o);
    if (lane == 0) watt[idx * 256 + k] = a;
}

// ---------------------------------------------------------------------------
// Fused: split-cast h into A2=[hi|lo] (K=512) + 9 attention dots. One wave/node.
// ---------------------------------------------------------------------------
__global__ __launch_bounds__(256) void cast_score(
    const float* __restrict__ h, const float* __restrict__ watt,
    bf16_t* __restrict__ A2, float* __restrict__ s_src, float* __restrict__ s_dst, int n) {
    const int node = (blockIdx.x * blockDim.x + threadIdx.x) >> 6;
    const int lane = threadIdx.x & 63;
    if (node >= n) return;
    float4 v = *(const float4*)(h + (size_t)node * 256 + lane * 4);
    bf16x4 hi = {(bf16_t)v.x, (bf16_t)v.y, (bf16_t)v.z, (bf16_t)v.w};
    bf16x4 lo = {(bf16_t)(v.x - (float)hi[0]), (bf16_t)(v.y - (float)hi[1]),
                 (bf16_t)(v.z - (float)hi[2]), (bf16_t)(v.w - (float)hi[3])};
    *(bf16x4*)(A2 + (size_t)node * 512 + lane * 4)       = hi;
    *(bf16x4*)(A2 + (size_t)node * 512 + 256 + lane * 4) = lo;
#pragma unroll
    for (int idx = 0; idx < 9; ++idx) {
        const float* wv = watt + idx * 256 + lane * 4;
        float a = v.x * wv[0] + v.y * wv[1] + v.z * wv[2] + v.w * wv[3];
        for (int o = 32; o > 0; o >>= 1) a += __shfl_xor(a, o);
        if (lane == 0) {
            if (idx < NREL) s_src[node * NREL + idx] = a;
            else            s_dst[node] = a;
        }
    }
}

// ---------------------------------------------------------------------------
// Pack B2 = [Wrel | Wroot]^T split layout [9*dout, 512]
// ---------------------------------------------------------------------------
__global__ void pack_bt(const float* __restrict__ Wrel, const float* __restrict__ Wroot,
                        bf16_t* __restrict__ B2, int di, int dout) {
    int n = blockIdx.x, k = threadIdx.x;
    int RD = NREL * dout;
    float v;
    if (n < RD) {
        int r = n / dout, j = n % dout;
        v = Wrel[(size_t)r * di * dout + (size_t)k * dout + j];
    } else {
        v = Wroot[(size_t)k * dout + (n - RD)];
    }
    bf16_t hi = (bf16_t)v;
    bf16_t lo = (bf16_t)(v - (float)hi);
    B2[(size_t)n * 512 + k]       = hi;
    B2[(size_t)n * 512 + 256 + k] = lo;
}

// ---------------------------------------------------------------------------
// Split-bf16 GEMM (K=512). 128x128 tile, BK=64 (128 B LDS rows = exact 32-bank
// wrap), period-8 XOR chunk swizzle (2-way bank aliasing only = free).
// 8 k-iters -> half the barriers of BK=32. hr written fp16; root fp32.
// ---------------------------------------------------------------------------
#define GBM 128
#define GBN 128
#define GBK 64

__global__ __launch_bounds__(256) void gemm_mfma(
    const bf16_t* __restrict__ A2, const bf16_t* __restrict__ B2,
    _Float16* __restrict__ hrf, float* __restrict__ root, int M, int dout) {
    constexpr int K = 512;
    const int RD = NREL * dout;
    __shared__ __align__(16) bf16_t As[GBM * GBK];   // 16 KB
    __shared__ __align__(16) bf16_t Bs[GBN * GBK];   // 16 KB
    const int tid  = threadIdx.x;
    const int lane = tid & 63;
    const int w    = tid >> 6;
    const int row0 = blockIdx.y * GBM;
    const int col0 = blockIdx.x * GBN;
    const int wm   = (w >> 1) * 64;
    const int wn   = (w & 1) * 64;

    f32x4 acc[4][4] = {};

    for (int kb = 0; kb < K; kb += GBK) {
#pragma unroll
        for (int i = 0; i < 4; ++i) {
            int c  = i * 256 + tid;        // chunk slot 0..1023 (16 B each)
            int r  = c >> 3;               // tile row (8 chunks/row)
            int cl = (c & 7) ^ (r & 7);    // logical k-chunk stored in this slot
            int ra = row0 + r; if (ra >= M) ra = M - 1;
            const bf16_t* ga = A2 + (size_t)ra * K + kb + cl * 8;
            __builtin_amdgcn_global_load_lds(
                (const __attribute__((address_space(1))) void*)ga,
                (__attribute__((address_space(3))) void*)(As + (size_t)c * 8), 16, 0, 0);
            const bf16_t* gb = B2 + (size_t)(col0 + r) * K + kb + cl * 8;
            __builtin_amdgcn_global_load_lds(
                (const __attribute__((address_space(1))) void*)gb,
                (__attribute__((address_space(3))) void*)(Bs + (size_t)c * 8), 16, 0, 0);
        }
        __syncthreads();

        const int q = lane >> 4;
#pragma unroll
        for (int kk = 0; kk < 2; ++kk) {
            const int cf = kk * 4 + q;     // logical chunk wanted
            bf16x8 af[4], bfr[4];
#pragma unroll
            for (int t = 0; t < 4; ++t) {
                int rr = wm + t * 16 + (lane & 15);
                af[t] = *(const bf16x8*)(As + rr * GBK + (cf ^ (rr & 7)) * 8);
                int rc = wn + t * 16 + (lane & 15);
                bfr[t] = *(const bf16x8*)(Bs + rc * GBK + (cf ^ (rc & 7)) * 8);
            }
#pragma unroll
            for (int mt = 0; mt < 4; ++mt)
#pragma unroll
                for (int nt = 0; nt < 4; ++nt)
                    acc[mt][nt] = __builtin_amdgcn_mfma_f32_16x16x32_bf16(
                        af[mt], bfr[nt], acc[mt][nt], 0, 0, 0);
        }
        __syncthreads();
    }

    const bool is_rel = (col0 < RD);
#pragma unroll
    for (int mt = 0; mt < 4; ++mt) {
#pragma unroll
        for (int reg = 0; reg < 4; ++reg) {
            int row = row0 + wm + mt * 16 + (lane >> 4) * 4 + reg;
            if (row >= M) continue;
#pragma unroll
            for (int nt = 0; nt < 4; ++nt) {
                int col = col0 + wn + nt * 16 + (lane & 15);
                float v = acc[mt][nt][reg];
                if (is_rel) hrf[(size_t)row * RD + col] = (_Float16)v;
                else        root[(size_t)row * dout + (col - RD)] = v;
            }
        }
    }
}

// ---------------------------------------------------------------------------
// Segment softmax + aggregation + epilogue. One wave per node; hr rows fp16.
// Batched: 64 edges scored in parallel, then register-broadcast (shfl) inner
// loop with 4 row-loads in flight. Denominator applied once at the end.
// ---------------------------------------------------------------------------
template <int DO, int MODE>
__global__ __launch_bounds__(256) void attn_agg(
    const int* __restrict__ off, const int* __restrict__ sorted,
    const float* __restrict__ s_src, const float* __restrict__ s_dst,
    const _Float16* __restrict__ hrf, const float* __restrict__ root,
    const int* __restrict__ relcnt, const float* __restrict__ relproj,
    const float* __restrict__ h_prev, float* __restrict__ out, int n) {
    const int node = (blockIdx.x * blockDim.x + threadIdx.x) >> 6;
    const int lane = threadIdx.x & 63;
    if (node >= n) return;
    const int beg = off[node];
    const int deg = off[node + 1] - beg;
    const float sdn = s_dst[node];
    constexpr int PER = DO / 64;
    float acc[PER];
#pragma unroll
    for (int j = 0; j < PER; ++j) acc[j] = 0.f;

    if (deg > 0) {
        float m = -1e30f;
        for (int e = lane; e < deg; e += 64) {
            int p = sorted[beg + e];
            float sc = s_src[(p >> 3) * NREL + (p & 7)] + sdn;
            sc = sc > 0.f ? sc : 0.2f * sc;
            m = fmaxf(m, sc);
        }
        for (int o = 32; o > 0; o >>= 1) m = fmaxf(m, __shfl_xor(m, o));

        float dsum = 0.f;
        for (int e0 = 0; e0 < deg; e0 += 64) {
            int e = e0 + lane;
            int p = 0; float ex = 0.f;
            if (e < deg) {
                p = sorted[beg + e];
                float sc = s_src[(p >> 3) * NREL + (p & 7)] + sdn;
                sc = sc > 0.f ? sc : 0.2f * sc;
                ex = __expf(sc - m);
                dsum += ex;
            }
            int cnt = deg - e0; if (cnt > 64) cnt = 64;
            int j = 0;
            for (; j + 4 <= cnt; j += 4) {
#pragma unroll
                for (int u = 0; u < 4; ++u) {
                    int pj = __shfl(p, j + u);
                    float exj = __shfl(ex, j + u);
                    const _Float16* row =
                        hrf + (size_t)(pj >> 3) * (NREL * DO) + (pj & 7) * DO;
                    if constexpr (PER == 4) {
                        h16x4 v = *(const h16x4*)(row + lane * 4);
                        acc[0] += exj * (float)v[0]; acc[1] += exj * (float)v[1];
                        acc[2] += exj * (float)v[2]; acc[3] += exj * (float)v[3];
                    } else {
                        h16x2 v = *(const h16x2*)(row + lane * 2);
                        acc[0] += exj * (float)v[0]; acc[1] += exj * (float)v[1];
                    }
                }
            }
            for (; j < cnt; ++j) {
                int pj = __shfl(p, j);
                float exj = __shfl(ex, j);
                const _Float16* row =
                    hrf + (size_t)(pj >> 3) * (NREL * DO) + (pj & 7) * DO;
                if constexpr (PER == 4) {
                    h16x4 v = *(const h16x4*)(row + lane * 4);
                    acc[0] += exj * (float)v[0]; acc[1] += exj * (float)v[1];
                    acc[2] += exj * (float)v[2]; acc[3] += exj * (float)v[3];
                } else {
                    h16x2 v = *(const h16x2*)(row + lane * 2);
                    acc[0] += exj * (float)v[0]; acc[1] += exj * (float)v[1];
                }
            }
        }
        for (int o = 32; o > 0; o >>= 1) dsum += __shfl_xor(dsum, o);
        float inv = 1.f / dsum;
#pragma unroll
        for (int j = 0; j < PER; ++j) acc[j] *= inv;
    }

    const int cbase = lane * PER;
    if constexpr (MODE == 0) {
        float rsum[PER];
#pragma unroll
        for (int j = 0; j < PER; ++j) rsum[j] = 0.f;
#pragma unroll
        for (int r = 0; r < NREL; ++r) {
            float cr = (float)relcnt[node * NREL + r];
            const float* rp = relproj + r * 256 + cbase;
#pragma unroll
            for (int j = 0; j < PER; ++j) rsum[j] += cr * rp[j];
        }
#pragma unroll
        for (int j = 0; j < PER; ++j) {
            int c = cbase + j;
            float r_ = root[(size_t)node * DO + c] + acc[j];
            float t  = r_ + rsum[j];
            t = t > 0.f ? t : 0.f;
            out[(size_t)node * DO + c] = h_prev[(size_t)node * DO + c] + t;
        }
    } else {
#pragma unroll
        for (int j = 0; j < PER; ++j) {
            int c = cbase + j;
            out[(size_t)node * DO + c] = root[(size_t)node * DO + c] + acc[j];
        }
    }
}

// ---------------------------------------------------------------------------
extern "C" void kernel_launch(void* const* d_in, const int* in_sizes, int n_in,
                              void* d_out, int out_size, void* d_ws, size_t ws_size,
                              hipStream_t stream) {
    const int N = NNODES, E = NEDGES;
    const float* x        = (const float*)d_in[0];
    const int*   ei       = (const int*)d_in[1];
    const int*   et       = (const int*)d_in[2];
    const float* rel_emb  = (const float*)d_in[3];
    const float* rpw      = (const float*)d_in[4];
    const float* rpb      = (const float*)d_in[5];
    const float* Wrel0    = (const float*)d_in[6];
    const float* Wroot0   = (const float*)d_in[7];
    const float* asrc0    = (const float*)d_in[8];
    const float* adst0    = (const float*)d_in[9];
    const float* Wrel1    = (const float*)d_in[10];
    const float* Wroot1   = (const float*)d_in[11];
    const float* asrc1    = (const float*)d_in[12];
    const float* adst1    = (const float*)d_in[13];
    const float* Wrel2    = (const float*)d_in[14];
    const float* Wroot2   = (const float*)d_in[15];
    const float* asrc2    = (const float*)d_in[16];
    const float* adst2    = (const float*)d_in[17];
    float* outp = (float*)d_out;

    // Workspace ~170 MB of 256 MiB budget.
    char* w = (char*)d_ws;
    auto alloc = [&](size_t bytes) { char* p = w; w += (bytes + 255) & ~(size_t)255; return p; };
    _Float16* hrf  = (_Float16*)alloc((size_t)N * 2048 * 2);  // 81.9 MB (L3-resident)
    float* root    = (float*)alloc((size_t)N * 256 * 4);
    float* h1      = (float*)alloc((size_t)N * 256 * 4);
    float* h2      = (float*)alloc((size_t)N * 256 * 4);
    float* relproj = (float*)alloc(NREL * 256 * 4);
    float* watt    = (float*)alloc(9 * 256 * 4);
    float* ssrc    = (float*)alloc((size_t)N * NREL * 4);
    float* sdst    = (float*)alloc((size_t)N * 4);
    bf16_t* A2     = (bf16_t*)alloc((size_t)N * 512 * 2);
    bf16_t* B2     = (bf16_t*)alloc((size_t)2304 * 512 * 2);
    int* deg       = (int*)alloc((size_t)N * 4);
    int* off       = (int*)alloc((size_t)(N + 1) * 4);
    int* cursor    = (int*)alloc((size_t)N * 4);
    int* relcnt    = (int*)alloc((size_t)N * NREL * 4);
    int* sorted    = (int*)alloc((size_t)E * 4);
    (void)ws_size; (void)in_sizes; (void)n_in; (void)out_size;

    hipMemsetAsync(deg, 0, (size_t)N * 4, stream);
    hipMemsetAsync(relcnt, 0, (size_t)N * NREL * 4, stream);

    const int EB = (E + 255) / 256;
    count_edges<<<EB, 256, 0, stream>>>(ei, et, deg, relcnt, E);
    scan_kernel<<<1, 1024, 0, stream>>>(deg, off, cursor, N);
    scatter_edges<<<EB, 256, 0, stream>>>(ei, et, cursor, sorted, E);
    rel_proj_k<<<NREL, 256, 0, stream>>>(rel_emb, rpw, rpb, relproj);

    const int ATB = (N + 3) / 4;
    const int WB  = (9 * 256) / 4;
    const int MB  = (N + GBM - 1) / GBM;

    // layer 0: x -> h1
    watt_k<<<WB, 256, 0, stream>>>(Wrel0, Wroot0, asrc0, adst0, watt, 256);
    cast_score<<<ATB, 256, 0, stream>>>(x, watt, A2, ssrc, sdst, N);
    pack_bt<<<2304, 256, 0, stream>>>(Wrel0, Wroot0, B2, 256, 256);
    { dim3 g(2304 / GBN, MB);
      gemm_mfma<<<g, 256, 0, stream>>>(A2, B2, hrf, root, N, 256); }
    attn_agg<256, 0><<<ATB, 256, 0, stream>>>(off, sorted, ssrc, sdst, hrf, root,
                                              relcnt, relproj, x, h1, N);
    // layer 1: h1 -> h2
    watt_k<<<WB, 256, 0, stream>>>(Wrel1, Wroot1, asrc1, adst1, watt, 256);
    cast_score<<<ATB, 256, 0, stream>>>(h1, watt, A2, ssrc, sdst, N);
    pack_bt<<<2304, 256, 0, stream>>>(Wrel1, Wroot1, B2, 256, 256);
    { dim3 g(2304 / GBN, MB);
      gemm_mfma<<<g, 256, 0, stream>>>(A2, B2, hrf, root, N, 256); }
    attn_agg<256, 0><<<ATB, 256, 0, stream>>>(off, sorted, ssrc, sdst, hrf, root,
                                              relcnt, relproj, h1, h2, N);
    // layer 2: h2 -> out
    watt_k<<<WB, 256, 0, stream>>>(Wrel2, Wroot2, asrc2, adst2, watt, 128);
    cast_score<<<ATB, 256, 0, stream>>>(h2, watt, A2, ssrc, sdst, N);
    pack_bt<<<1152, 256, 0, stream>>>(Wrel2, Wroot2, B2, 256, 128);
    { dim3 g(1152 / GBN, MB);
      gemm_mfma<<<g, 256, 0, stream>>>(A2, B2, hrf, root, N, 128); }
    attn_agg<128, 1><<<ATB, 256, 0, stream>>>(off, sorted, ssrc, sdst, hrf, root,
                                              nullptr, nullptr, nullptr, outp, N);
}

// Round 7
// 566.568 us; speedup vs baseline: 2.4525x; 1.0374x over previous
//
#include <hip/hip_runtime.h>
#include <hip/hip_bf16.h>
#include <math.h>

#define NNODES 20000
#define NEDGES 400000
#define NREL 8

typedef _Float16 h16_t;
typedef _Float16 h16x8 __attribute__((ext_vector_type(8)));
typedef _Float16 h16x4 __attribute__((ext_vector_type(4)));
typedef _Float16 h16x2 __attribute__((ext_vector_type(2)));
typedef float f32x4 __attribute__((ext_vector_type(4)));

struct W3 {
    const float* Wrel[3];
    const float* Wroot[3];
    const float* asrc[3];
    const float* adst[3];
    h16_t* B2[3];
};

// ---------------------------------------------------------------------------
// Edge preprocessing
// ---------------------------------------------------------------------------
__global__ void count_edges(const int* __restrict__ ei, const int* __restrict__ et,
                            int* __restrict__ deg, int* __restrict__ rel_cnt, int E) {
    int e = blockIdx.x * blockDim.x + threadIdx.x;
    if (e >= E) return;
    int d = ei[E + e];
    atomicAdd(&deg[d], 1);
    atomicAdd(&rel_cnt[d * NREL + et[e]], 1);
}

__global__ void scan_kernel(const int* __restrict__ deg, int* __restrict__ off,
                            int* __restrict__ cursor, int n) {
    __shared__ int wsum[16];
    __shared__ int carry_s;
    const int lane = threadIdx.x & 63, wid = threadIdx.x >> 6;
    if (threadIdx.x == 0) carry_s = 0;
    __syncthreads();
    for (int base = 0; base < n; base += 1024) {
        int i = base + (int)threadIdx.x;
        int v = (i < n) ? deg[i] : 0;
        int s = v;
#pragma unroll
        for (int o = 1; o < 64; o <<= 1) {
            int t = __shfl_up(s, o);
            if (lane >= o) s += t;
        }
        if (lane == 63) wsum[wid] = s;
        __syncthreads();
        if (wid == 0) {
            int ws = (lane < 16) ? wsum[lane] : 0;
#pragma unroll
            for (int o = 1; o < 16; o <<= 1) {
                int t = __shfl_up(ws, o);
                if (lane >= o) ws += t;
            }
            if (lane < 16) wsum[lane] = ws;
        }
        __syncthreads();
        int wbase = (wid == 0) ? 0 : wsum[wid - 1];
        int excl = carry_s + wbase + s - v;
        if (i < n) { off[i] = excl; cursor[i] = excl; }
        __syncthreads();
        if (threadIdx.x == 0) carry_s += wsum[15];
        __syncthreads();
    }
    if (threadIdx.x == 0) off[n] = carry_s;
}

__global__ void scatter_edges(const int* __restrict__ ei, const int* __restrict__ et,
                              int* __restrict__ cursor, int* __restrict__ sorted, int E) {
    int e = blockIdx.x * blockDim.x + threadIdx.x;
    if (e >= E) return;
    int d = ei[E + e];
    int pos = atomicAdd(&cursor[d], 1);
    sorted[pos] = (ei[e] << 3) | et[e];
}

// ---------------------------------------------------------------------------
// rel_proj = rel_emb @ rel_proj_w + b  (tiny)
// ---------------------------------------------------------------------------
__global__ void rel_proj_k(const float* __restrict__ rel_emb, const float* __restrict__ W,
                           const float* __restrict__ b, float* __restrict__ rel_proj) {
    int r = blockIdx.x, j = threadIdx.x;
    float acc = b[j];
    for (int i = 0; i < 256; ++i) acc += rel_emb[r * 256 + i] * W[i * 256 + j];
    rel_proj[r * 256 + j] = acc;
}

// ---------------------------------------------------------------------------
// watt[l][idx][k]: idx<8 -> Wrel_r @ att_src ; idx==8 -> Wroot @ att_dst
// all 3 layers in one launch.
// ---------------------------------------------------------------------------
__global__ __launch_bounds__(256) void watt3_k(W3 w, float* __restrict__ watt) {
    const int wg = (blockIdx.x * blockDim.x + threadIdx.x) >> 6;
    const int lane = threadIdx.x & 63;
    if (wg >= 3 * 9 * 256) return;
    const int layer = wg / (9 * 256);
    const int rem = wg % (9 * 256);
    const int idx = rem >> 8, k = rem & 255;
    const int dout = (layer == 2) ? 128 : 256;
    float a = 0.f;
    if (idx < NREL) {
        const float* wrow = w.Wrel[layer] + ((size_t)idx * 256 + k) * dout;
        const float* att = w.asrc[layer];
        for (int j = lane; j < dout; j += 64) a += wrow[j] * att[j];
    } else {
        const float* wrow = w.Wroot[layer] + (size_t)k * dout;
        const float* att = w.adst[layer];
        for (int j = lane; j < dout; j += 64) a += wrow[j] * att[j];
    }
    for (int o = 32; o > 0; o >>= 1) a += __shfl_xor(a, o);
    if (lane == 0) watt[(layer * 9 + idx) * 256 + k] = a;
}

// ---------------------------------------------------------------------------
// Pack B2_l = [Wrel_l | Wroot_l]^T split-fp16 [9*dout, 512], all layers.
// ---------------------------------------------------------------------------
__global__ void pack3_k(W3 w) {
    int b = blockIdx.x, k = threadIdx.x;
    int layer, n;
    if (b < 2304)      { layer = 0; n = b; }
    else if (b < 4608) { layer = 1; n = b - 2304; }
    else               { layer = 2; n = b - 4608; }
    const int dout = (layer == 2) ? 128 : 256;
    const int RD = NREL * dout;
    float v;
    if (n < RD) {
        int r = n / dout, j = n % dout;
        v = w.Wrel[layer][(size_t)r * 256 * dout + (size_t)k * dout + j];
    } else {
        v = w.Wroot[layer][(size_t)k * dout + (n - RD)];
    }
    h16_t hi = (h16_t)v;
    h16_t lo = (h16_t)(v - (float)hi);
    h16_t* B2 = w.B2[layer];
    B2[(size_t)n * 512 + k]       = hi;
    B2[(size_t)n * 512 + 256 + k] = lo;
}

// ---------------------------------------------------------------------------
// Layer-0 only: split-cast x into A2=[hi|lo] + 9 attention dots. One wave/node.
// ---------------------------------------------------------------------------
__global__ __launch_bounds__(256) void cast_score(
    const float* __restrict__ h, const float* __restrict__ watt,
    h16_t* __restrict__ A2, float* __restrict__ s_src, float* __restrict__ s_dst, int n) {
    const int node = (blockIdx.x * blockDim.x + threadIdx.x) >> 6;
    const int lane = threadIdx.x & 63;
    if (node >= n) return;
    float4 v = *(const float4*)(h + (size_t)node * 256 + lane * 4);
    h16x4 hi = {(h16_t)v.x, (h16_t)v.y, (h16_t)v.z, (h16_t)v.w};
    h16x4 lo = {(h16_t)(v.x - (float)hi[0]), (h16_t)(v.y - (float)hi[1]),
                (h16_t)(v.z - (float)hi[2]), (h16_t)(v.w - (float)hi[3])};
    *(h16x4*)(A2 + (size_t)node * 512 + lane * 4)       = hi;
    *(h16x4*)(A2 + (size_t)node * 512 + 256 + lane * 4) = lo;
#pragma unroll
    for (int idx = 0; idx < 9; ++idx) {
        const float* wv = watt + idx * 256 + lane * 4;
        float a = v.x * wv[0] + v.y * wv[1] + v.z * wv[2] + v.w * wv[3];
        for (int o = 32; o > 0; o >>= 1) a += __shfl_xor(a, o);
        if (lane == 0) {
            if (idx < NREL) s_src[node * NREL + idx] = a;
            else            s_dst[node] = a;
        }
    }
}

// ---------------------------------------------------------------------------
// Split-fp16 GEMM (K=512): C = Ahi*Bhi + Alo*Blo (cross terms ~2^-12, dropped).
// 128x128 tile, BK=64, 4 waves, 4x4 16x16x32 f16 frags, global_load_lds w16,
// period-8 XOR chunk swizzle (conflict-free). hr fp16; root fp32.
// ---------------------------------------------------------------------------
#define GBM 128
#define GBN 128
#define GBK 64

__global__ __launch_bounds__(256) void gemm_mfma(
    const h16_t* __restrict__ A2, const h16_t* __restrict__ B2,
    h16_t* __restrict__ hrf, float* __restrict__ root, int M, int dout) {
    constexpr int K = 512;
    const int RD = NREL * dout;
    __shared__ __align__(16) h16_t As[GBM * GBK];
    __shared__ __align__(16) h16_t Bs[GBN * GBK];
    const int tid  = threadIdx.x;
    const int lane = tid & 63;
    const int w    = tid >> 6;
    const int row0 = blockIdx.y * GBM;
    const int col0 = blockIdx.x * GBN;
    const int wm   = (w >> 1) * 64;
    const int wn   = (w & 1) * 64;

    f32x4 acc[4][4] = {};

    for (int kb = 0; kb < K; kb += GBK) {
#pragma unroll
        for (int i = 0; i < 4; ++i) {
            int c  = i * 256 + tid;
            int r  = c >> 3;
            int cl = (c & 7) ^ (r & 7);
            int ra = row0 + r; if (ra >= M) ra = M - 1;
            const h16_t* ga = A2 + (size_t)ra * K + kb + cl * 8;
            __builtin_amdgcn_global_load_lds(
                (const __attribute__((address_space(1))) void*)ga,
                (__attribute__((address_space(3))) void*)(As + (size_t)c * 8), 16, 0, 0);
            const h16_t* gb = B2 + (size_t)(col0 + r) * K + kb + cl * 8;
            __builtin_amdgcn_global_load_lds(
                (const __attribute__((address_space(1))) void*)gb,
                (__attribute__((address_space(3))) void*)(Bs + (size_t)c * 8), 16, 0, 0);
        }
        __syncthreads();

        const int q = lane >> 4;
#pragma unroll
        for (int kk = 0; kk < 2; ++kk) {
            const int cf = kk * 4 + q;
            h16x8 af[4], bfr[4];
#pragma unroll
            for (int t = 0; t < 4; ++t) {
                int rr = wm + t * 16 + (lane & 15);
                af[t] = *(const h16x8*)(As + rr * GBK + (cf ^ (rr & 7)) * 8);
                int rc = wn + t * 16 + (lane & 15);
                bfr[t] = *(const h16x8*)(Bs + rc * GBK + (cf ^ (rc & 7)) * 8);
            }
#pragma unroll
            for (int mt = 0; mt < 4; ++mt)
#pragma unroll
                for (int nt = 0; nt < 4; ++nt)
                    acc[mt][nt] = __builtin_amdgcn_mfma_f32_16x16x32_f16(
                        af[mt], bfr[nt], acc[mt][nt], 0, 0, 0);
        }
        __syncthreads();
    }

    const bool is_rel = (col0 < RD);
#pragma unroll
    for (int mt = 0; mt < 4; ++mt) {
#pragma unroll
        for (int reg = 0; reg < 4; ++reg) {
            int row = row0 + wm + mt * 16 + (lane >> 4) * 4 + reg;
            if (row >= M) continue;
#pragma unroll
            for (int nt = 0; nt < 4; ++nt) {
                int col = col0 + wn + nt * 16 + (lane & 15);
                float v = acc[mt][nt][reg];
                if (is_rel) hrf[(size_t)row * RD + col] = (h16_t)v;
                else        root[(size_t)row * dout + (col - RD)] = v;
            }
        }
    }
}

// ---------------------------------------------------------------------------
// Segment softmax + aggregation + epilogue. One wave per node; hr rows fp16.
// deg<=64 fast path (single gather). 8 row-loads in flight via shfl broadcast.
// MODE 0 additionally emits the NEXT layer's A2 split + attention scores.
// ---------------------------------------------------------------------------
template <int DO, int MODE>
__global__ __launch_bounds__(256) void attn_agg(
    const int* __restrict__ off, const int* __restrict__ sorted,
    const float* __restrict__ s_src, const float* __restrict__ s_dst,
    const h16_t* __restrict__ hrf, const float* __restrict__ root,
    const int* __restrict__ relcnt, const float* __restrict__ relproj,
    const float* __restrict__ h_prev, float* __restrict__ out,
    const float* __restrict__ watt_next, h16_t* __restrict__ A2out,
    float* __restrict__ ssrc_out, float* __restrict__ sdst_out, int n) {
    const int node = (blockIdx.x * blockDim.x + threadIdx.x) >> 6;
    const int lane = threadIdx.x & 63;
    if (node >= n) return;
    const int beg = off[node];
    const int deg = off[node + 1] - beg;
    const float sdn = s_dst[node];
    constexpr int PER = DO / 64;
    float acc[PER];
#pragma unroll
    for (int j = 0; j < PER; ++j) acc[j] = 0.f;

    auto rowload = [&](int pj, float exj) {
        const h16_t* row = hrf + (size_t)(pj >> 3) * (NREL * DO) + (pj & 7) * DO;
        if constexpr (PER == 4) {
            h16x4 v = *(const h16x4*)(row + lane * 4);
            acc[0] += exj * (float)v[0]; acc[1] += exj * (float)v[1];
            acc[2] += exj * (float)v[2]; acc[3] += exj * (float)v[3];
        } else {
            h16x2 v = *(const h16x2*)(row + lane * 2);
            acc[0] += exj * (float)v[0]; acc[1] += exj * (float)v[1];
        }
    };

    if (deg > 0) {
        float inv;
        if (deg <= 64) {
            // fast path: one gather, scores stay in registers
            int p = 0; float sc = -1e30f;
            if (lane < deg) {
                p = sorted[beg + lane];
                sc = s_src[(p >> 3) * NREL + (p & 7)] + sdn;
                sc = sc > 0.f ? sc : 0.2f * sc;
            }
            float m = sc;
            for (int o = 32; o > 0; o >>= 1) m = fmaxf(m, __shfl_xor(m, o));
            float ex = (lane < deg) ? __expf(sc - m) : 0.f;
            float dsum = ex;
            for (int o = 32; o > 0; o >>= 1) dsum += __shfl_xor(dsum, o);
            int j = 0;
            for (; j + 8 <= deg; j += 8) {
#pragma unroll
                for (int u = 0; u < 8; ++u)
                    rowload(__shfl(p, j + u), __shfl(ex, j + u));
            }
            for (; j < deg; ++j) rowload(__shfl(p, j), __shfl(ex, j));
            inv = 1.f / dsum;
        } else {
            float m = -1e30f;
            for (int e = lane; e < deg; e += 64) {
                int p = sorted[beg + e];
                float sc = s_src[(p >> 3) * NREL + (p & 7)] + sdn;
                sc = sc > 0.f ? sc : 0.2f * sc;
                m = fmaxf(m, sc);
            }
            for (int o = 32; o > 0; o >>= 1) m = fmaxf(m, __shfl_xor(m, o));
            float dsum = 0.f;
            for (int e0 = 0; e0 < deg; e0 += 64) {
                int e = e0 + lane;
                int p = 0; float ex = 0.f;
                if (e < deg) {
                    p = sorted[beg + e];
                    float sc = s_src[(p >> 3) * NREL + (p & 7)] + sdn;
                    sc = sc > 0.f ? sc : 0.2f * sc;
                    ex = __expf(sc - m);
                    dsum += ex;
                }
                int cnt = deg - e0; if (cnt > 64) cnt = 64;
                int j = 0;
                for (; j + 8 <= cnt; j += 8) {
#pragma unroll
                    for (int u = 0; u < 8; ++u)
                        rowload(__shfl(p, j + u), __shfl(ex, j + u));
                }
                for (; j < cnt; ++j) rowload(__shfl(p, j), __shfl(ex, j));
            }
            for (int o = 32; o > 0; o >>= 1) dsum += __shfl_xor(dsum, o);
            inv = 1.f / dsum;
        }
#pragma unroll
        for (int j = 0; j < PER; ++j) acc[j] *= inv;
    }

    const int cbase = lane * PER;
    if constexpr (MODE == 0) {
        float rsum[PER];
#pragma unroll
        for (int j = 0; j < PER; ++j) rsum[j] = 0.f;
#pragma unroll
        for (int r = 0; r < NREL; ++r) {
            float cr = (float)relcnt[node * NREL + r];
            const float* rp = relproj + r * 256 + cbase;
#pragma unroll
            for (int j = 0; j < PER; ++j) rsum[j] += cr * rp[j];
        }
        float t[PER];
#pragma unroll
        for (int j = 0; j < PER; ++j) {
            int c = cbase + j;
            float r_ = root[(size_t)node * DO + c] + acc[j];
            float u = r_ + rsum[j];
            u = u > 0.f ? u : 0.f;
            t[j] = h_prev[(size_t)node * DO + c] + u;
            out[(size_t)node * DO + c] = t[j];
        }
        // fused next-layer prep: split-cast + 9 attention dots
        h16x4 hi, lo;
#pragma unroll
        for (int j = 0; j < PER; ++j) {
            hi[j] = (h16_t)t[j];
            lo[j] = (h16_t)(t[j] - (float)hi[j]);
        }
        *(h16x4*)(A2out + (size_t)node * 512 + cbase)       = hi;
        *(h16x4*)(A2out + (size_t)node * 512 + 256 + cbase) = lo;
#pragma unroll
        for (int idx = 0; idx < 9; ++idx) {
            const float* wv = watt_next + idx * 256 + cbase;
            float a = 0.f;
#pragma unroll
            for (int j = 0; j < PER; ++j) a += t[j] * wv[j];
            for (int o = 32; o > 0; o >>= 1) a += __shfl_xor(a, o);
            if (lane == 0) {
                if (idx < NREL) ssrc_out[node * NREL + idx] = a;
                else            sdst_out[node] = a;
            }
        }
    } else {
#pragma unroll
        for (int j = 0; j < PER; ++j) {
            int c = cbase + j;
            out[(size_t)node * DO + c] = root[(size_t)node * DO + c] + acc[j];
        }
    }
}

// ---------------------------------------------------------------------------
extern "C" void kernel_launch(void* const* d_in, const int* in_sizes, int n_in,
                              void* d_out, int out_size, void* d_ws, size_t ws_size,
                              hipStream_t stream) {
    const int N = NNODES, E = NEDGES;
    const float* x        = (const float*)d_in[0];
    const int*   ei       = (const int*)d_in[1];
    const int*   et       = (const int*)d_in[2];
    const float* rel_emb  = (const float*)d_in[3];
    const float* rpw      = (const float*)d_in[4];
    const float* rpb      = (const float*)d_in[5];
    float* outp = (float*)d_out;

    W3 w3;
    for (int l = 0; l < 3; ++l) {
        w3.Wrel[l]  = (const float*)d_in[6 + 4 * l];
        w3.Wroot[l] = (const float*)d_in[7 + 4 * l];
        w3.asrc[l]  = (const float*)d_in[8 + 4 * l];
        w3.adst[l]  = (const float*)d_in[9 + 4 * l];
    }

    // Workspace ~175 MB of 256 MiB budget.
    char* w = (char*)d_ws;
    auto alloc = [&](size_t bytes) { char* p = w; w += (bytes + 255) & ~(size_t)255; return p; };
    h16_t* hrf     = (h16_t*)alloc((size_t)N * 2048 * 2);   // 81.9 MB
    float* root    = (float*)alloc((size_t)N * 256 * 4);
    float* h1      = (float*)alloc((size_t)N * 256 * 4);
    float* h2      = (float*)alloc((size_t)N * 256 * 4);
    float* relproj = (float*)alloc(NREL * 256 * 4);
    float* watt    = (float*)alloc(3 * 9 * 256 * 4);
    float* ssrcA   = (float*)alloc((size_t)N * NREL * 4);
    float* sdstA   = (float*)alloc((size_t)N * 4);
    float* ssrcB   = (float*)alloc((size_t)N * NREL * 4);
    float* sdstB   = (float*)alloc((size_t)N * 4);
    h16_t* A2      = (h16_t*)alloc((size_t)N * 512 * 2);    // 20.5 MB
    w3.B2[0]       = (h16_t*)alloc((size_t)2304 * 512 * 2);
    w3.B2[1]       = (h16_t*)alloc((size_t)2304 * 512 * 2);
    w3.B2[2]       = (h16_t*)alloc((size_t)1152 * 512 * 2);
    int* deg       = (int*)alloc((size_t)N * 4);
    int* off       = (int*)alloc((size_t)(N + 1) * 4);
    int* cursor    = (int*)alloc((size_t)N * 4);
    int* relcnt    = (int*)alloc((size_t)N * NREL * 4);
    int* sorted    = (int*)alloc((size_t)E * 4);
    (void)ws_size; (void)in_sizes; (void)n_in; (void)out_size;

    hipMemsetAsync(deg, 0, (size_t)N * 4, stream);
    hipMemsetAsync(relcnt, 0, (size_t)N * NREL * 4, stream);

    const int EB = (E + 255) / 256;
    count_edges<<<EB, 256, 0, stream>>>(ei, et, deg, relcnt, E);
    scan_kernel<<<1, 1024, 0, stream>>>(deg, off, cursor, N);
    scatter_edges<<<EB, 256, 0, stream>>>(ei, et, cursor, sorted, E);
    rel_proj_k<<<NREL, 256, 0, stream>>>(rel_emb, rpw, rpb, relproj);
    watt3_k<<<(3 * 9 * 256) / 4, 256, 0, stream>>>(w3, watt);
    pack3_k<<<5760, 256, 0, stream>>>(w3);

    const int ATB = (N + 3) / 4;
    const int MB  = (N + GBM - 1) / GBM;

    // layer 0: x -> h1
    cast_score<<<ATB, 256, 0, stream>>>(x, watt, A2, ssrcA, sdstA, N);
    { dim3 g(2304 / GBN, MB);
      gemm_mfma<<<g, 256, 0, stream>>>(A2, w3.B2[0], hrf, root, N, 256); }
    attn_agg<256, 0><<<ATB, 256, 0, stream>>>(off, sorted, ssrcA, sdstA, hrf, root,
                                              relcnt, relproj, x, h1,
                                              watt + 9 * 256, A2, ssrcB, sdstB, N);
    // layer 1: h1 -> h2
    { dim3 g(2304 / GBN, MB);
      gemm_mfma<<<g, 256, 0, stream>>>(A2, w3.B2[1], hrf, root, N, 256); }
    attn_agg<256, 0><<<ATB, 256, 0, stream>>>(off, sorted, ssrcB, sdstB, hrf, root,
                                              relcnt, relproj, h1, h2,
                                              watt + 2 * 9 * 256, A2, ssrcA, sdstA, N);
    // layer 2: h2 -> out
    { dim3 g(1152 / GBN, MB);
      gemm_mfma<<<g, 256, 0, stream>>>(A2, w3.B2[2], hrf, root, N, 128); }
    attn_agg<128, 1><<<ATB, 256, 0, stream>>>(off, sorted, ssrcA, sdstA, hrf, root,
                                              nullptr, nullptr, nullptr, outp,
                                              nullptr, nullptr, nullptr, nullptr, N);
}